// Round 16
// baseline (52.482 us; speedup 1.0000x reference)
//
#include <hip/hip_runtime.h>
#include <hip/hip_bf16.h>
#include <cstddef>
#include <cstdint>

#define BS    8
#define M_PTS 1024
#define N_PTS 4096
#define C0    256
#define C1    128
#define C2    256
#define K1DIM 384   // C0 + C1

typedef __attribute__((ext_vector_type(8))) short bf16x8;
typedef __attribute__((ext_vector_type(4))) float f32x4;

__device__ __forceinline__ ushort f2bf(float f) {
  union { float f; unsigned u; } v; v.f = f;
  unsigned r = v.u + 0x7fffu + ((v.u >> 16) & 1u);   // RNE
  return (ushort)(r >> 16);
}
__device__ __forceinline__ ushort bf16c(float f) {
  return __builtin_bit_cast(ushort, __float2bfloat16(f));
}

// ---------------------------------------------------------------------------
// Prep: blocks [0,384) convert W1/W2 to bf16 MFMA A-frag order (unchanged);
// blocks [384,512) compute G^T = (W1[:, :256] @ feats)^T per batch via MFMA.
//   gemmG block: batch bz = id2 & 7 (XCD-pinned), m-tile mt = id2 >> 3.
//   B-tile (feats k=0..255 x 64 cols) staged to LDS in frag order (32 KB).
//   A-frags built from W1 f32 rows on the fly. Output stored transposed:
//   G^T[m, r] — lane (c,g) holds rows r = mb*16+g*4+reg at col m (f32x4 store).
// ---------------------------------------------------------------------------
__global__ __launch_bounds__(256) void prep_k(
    const float* __restrict__ feats, const float* __restrict__ W1,
    const float* __restrict__ W2, ushort* __restrict__ W1f,
    ushort* __restrict__ W2f, float* __restrict__ Gt) {
  const int t = threadIdx.x;
  if (blockIdx.x < 384) {
    const int id = blockIdx.x * 256 + t;
    if (id < C2 * K1DIM) {
      int m = id / K1DIM, k = id - m * K1DIM;
      int off = (((m >> 4) * 12 + (k >> 5)) * 4 + ((k >> 3) & 3)) * 128 + (m & 15) * 8 + (k & 7);
      W1f[off] = f2bf(W1[id]);
    }
    if (id < C2 * C2) {
      int m = id >> 8, k = id & 255;
      int off = (((m >> 4) * 8 + (k >> 5)) * 4 + ((k >> 3) & 3)) * 128 + (m & 15) * 8 + (k & 7);
      W2f[off] = f2bf(W2[id]);
    }
    return;
  }
  // ---- gemmG ----
  __shared__ ushort Bt[16384];                    // 256k x 64n bf16 frag order
  const int id2 = blockIdx.x - 384;               // 0..127
  const int bz = id2 & 7;                         // XCD-pinned batch
  const int m0 = (id2 >> 3) * 64;                 // point-column tile base
  const float* fb = feats + (size_t)bz * C0 * M_PTS;

  // stage B: thread t iter it: row c = it*16 + (t>>4), cols nl..nl+3
#pragma unroll
  for (int it = 0; it < 16; ++it) {
    const int cc = it * 16 + (t >> 4);
    const int nl = (t & 15) * 4;
    const float4 v = *(const float4*)(fb + (size_t)cc * M_PTS + m0 + nl);
    const int kq = cc >> 3, ko = cc & 7;
    Bt[(kq * 64 + ((nl + 0) ^ (kq & 7))) * 8 + ko] = bf16c(v.x);
    Bt[(kq * 64 + ((nl + 1) ^ (kq & 7))) * 8 + ko] = bf16c(v.y);
    Bt[(kq * 64 + ((nl + 2) ^ (kq & 7))) * 8 + ko] = bf16c(v.z);
    Bt[(kq * 64 + ((nl + 3) ^ (kq & 7))) * 8 + ko] = bf16c(v.w);
  }
  __syncthreads();

  const int wv = t >> 6, l = t & 63, c = l & 15, g = l >> 4;
  f32x4 acc[4][4];
#pragma unroll
  for (int i = 0; i < 4; ++i)
#pragma unroll
    for (int j = 0; j < 4; ++j) acc[i][j] = (f32x4){0.f, 0.f, 0.f, 0.f};

  for (int kb = 0; kb < 8; ++kb) {
    const int kqg = kb * 4 + g;
    bf16x8 bfr[4], afr[4];
#pragma unroll
    for (int j = 0; j < 4; ++j)
      bfr[j] = *reinterpret_cast<const bf16x8*>(&Bt[(kqg * 64 + ((j * 16 + c) ^ (kqg & 7))) * 8]);
#pragma unroll
    for (int i = 0; i < 4; ++i) {
      const float* wr = W1 + (size_t)((wv * 4 + i) * 16 + c) * K1DIM + kb * 32 + g * 8;
      const float4 a0 = *(const float4*)wr;
      const float4 a1 = *(const float4*)(wr + 4);
      bf16x8 af;
      af[0] = (short)bf16c(a0.x); af[1] = (short)bf16c(a0.y);
      af[2] = (short)bf16c(a0.z); af[3] = (short)bf16c(a0.w);
      af[4] = (short)bf16c(a1.x); af[5] = (short)bf16c(a1.y);
      af[6] = (short)bf16c(a1.z); af[7] = (short)bf16c(a1.w);
      afr[i] = af;
    }
#pragma unroll
    for (int i = 0; i < 4; ++i)
#pragma unroll
      for (int j = 0; j < 4; ++j)
        acc[i][j] = __builtin_amdgcn_mfma_f32_16x16x32_bf16(afr[i], bfr[j], acc[i][j], 0, 0, 0);
  }

  float* gtb = Gt + (size_t)bz * M_PTS * C2;
#pragma unroll
  for (int i = 0; i < 4; ++i)
#pragma unroll
    for (int j = 0; j < 4; ++j)
      *reinterpret_cast<float4*>(gtb + (size_t)(m0 + j * 16 + c) * C2 + (wv * 4 + i) * 16 + g * 4)
          = *reinterpret_cast<float4*>(&acc[i][j]);
}

// ---------------------------------------------------------------------------
// Fully fused per 32-query tile, 256 threads / 4 waves, LDS 25344 B.
// r15 scan (doubled coords, exact select/merge) -> idx/w via LDS ->
// f32 gather of G^T rows DIRECTLY into MFMA accumulators (up-part of GEMM1)
// -> GEMM1 over skip only (K=128, W1f kb 8..11) -> GEMM2 (r15 verbatim).
// ---------------------------------------------------------------------------
__global__ __launch_bounds__(256, 4) void fp_fused_k(
    const float* __restrict__ xyz,      // (BS, M, 3)
    const float* __restrict__ pxyz,     // (BS, N, 3)
    const float* __restrict__ Gt,       // (BS, M, C2) f32 = (W1a@feats)^T
    const float* __restrict__ skip,     // (BS, C1, N) f32
    const ushort* __restrict__ W1f,
    const float* __restrict__ b1,
    const ushort* __restrict__ W2f,
    const float* __restrict__ b2,
    float* __restrict__ out) {          // (BS, C2, N) f32
  __shared__ float4 smemq[1584];                  // 25344 B
  float4* pts4  = smemq;                          // [0,16384): 512 pairs
  ushort* pfB   = (ushort*)smemq + 8192;          // [16384,24576): 128x32 bf16 skip
  int*    idx_s = (int*)((char*)smemq + 24576);   // [32][3]
  float*  w_s   = (float*)((char*)smemq + 24960); // [32][3]
  ushort* hbuf  = (ushort*)smemq;                 // [0,16384): 256x32 bf16 (aliases pts)

  const int t  = threadIdx.x;
  const int b  = blockIdx.x & 7;                  // XCD-pinned batch
  const int n0 = (blockIdx.x >> 3) * 32;
  const int wv = t >> 6, l = t & 63;
  const int q  = t >> 3, sub = t & 7;

  const float qx = pxyz[((size_t)b * N_PTS + n0 + q) * 3 + 0];
  const float qy = pxyz[((size_t)b * N_PTS + n0 + q) * 3 + 1];
  const float qz = pxyz[((size_t)b * N_PTS + n0 + q) * 3 + 2];

  // ---- stage pts (DOUBLED coords), slot U = p ^ ((p>>6)&7) ----
#pragma unroll
  for (int it = 0; it < 2; ++it) {
    const int p = t + it * 256;
    const float2* xb = (const float2*)(xyz + (size_t)b * 3 * M_PTS + 6 * p);
    const float2 A = xb[0], B = xb[1], C = xb[2];
    const float x0 = A.x, y0 = A.y, z0 = B.x, x1 = B.y, y1 = C.x, z1 = C.y;
    const float s0 = __fadd_rn(__fadd_rn(__fmul_rn(x0, x0), __fmul_rn(y0, y0)),
                               __fmul_rn(z0, z0));
    const float s1 = __fadd_rn(__fadd_rn(__fmul_rn(x1, x1), __fmul_rn(y1, y1)),
                               __fmul_rn(z1, z1));
    const int U = p ^ ((p >> 6) & 7);
    pts4[U * 2 + 0] = (float4){x0 + x0, x1 + x1, y0 + y0, y1 + y1};
    pts4[U * 2 + 1] = (float4){z0 + z0, z1 + z1, s0, s1};
  }

  // ---- skip -> pfB directly (bf16, frag order, k-local 0..127) ----
#pragma unroll
  for (int it = 0; it < 8; ++it) {
    const int id = t + it * 256;
    const int r2 = id >> 5, nn = id & 31;
    const float s0v = skip[((size_t)b * C1 + 2 * r2 + 0) * N_PTS + n0 + nn];
    const float s1v = skip[((size_t)b * C1 + 2 * r2 + 1) * N_PTS + n0 + nn];
    const int kl = 2 * r2;
    const int kq = kl >> 3;
    ushort2 sv; sv.x = bf16c(s0v); sv.y = bf16c(s1v);
    *reinterpret_cast<ushort2*>(&pfB[(kq * 32 + (nn ^ (kq & 7))) * 8 + (kl & 7)]) = sv;
  }

  const float qq = __fadd_rn(__fadd_rn(__fmul_rn(qx, qx), __fmul_rn(qy, qy)),
                             __fmul_rn(qz, qz));
  __syncthreads();   // barrier 1: pts staged

  // ---- scan: 8 subs x 64 pairs; d = (qq - dot2) + s2 (bit-exact) ----
  float d0 = 3.4e38f, d1 = 3.4e38f, d2 = 3.4e38f;
  int   i0 = 0, i1 = 0, i2 = 0;
  {
    int pe[8];
#pragma unroll
    for (int e = 0; e < 8; ++e) pe[e] = (sub * 64 + (e ^ sub)) * 2;
    for (int jb = 0; jb < 8; ++jb) {
#pragma unroll
      for (int e = 0; e < 8; ++e) {
        const float4 A  = pts4[pe[e] + jb * 16];
        const float4 Bv = pts4[pe[e] + jb * 16 + 1];
        {
          const float dot2 = __fadd_rn(__fadd_rn(__fmul_rn(qx, A.x), __fmul_rn(qy, A.z)),
                                       __fmul_rn(qz, Bv.x));
          const float d = __fadd_rn(__fsub_rn(qq, dot2), Bv.z);
          const int m = jb * 16 + 2 * e;
          const bool c0 = d < d0, c1 = d < d1, c2 = d < d2;
          i2 = c1 ? i1 : (c2 ? m : i2);
          i1 = c0 ? i0 : (c1 ? m : i1);
          i0 = c0 ? m : i0;
          d2 = __builtin_amdgcn_fmed3f(d, d1, d2);
          d1 = __builtin_amdgcn_fmed3f(d, d0, d1);
          d0 = fminf(d, d0);
        }
        {
          const float dot2 = __fadd_rn(__fadd_rn(__fmul_rn(qx, A.y), __fmul_rn(qy, A.w)),
                                       __fmul_rn(qz, Bv.y));
          const float d = __fadd_rn(__fsub_rn(qq, dot2), Bv.w);
          const int m = jb * 16 + 2 * e + 1;
          const bool c0 = d < d0, c1 = d < d1, c2 = d < d2;
          i2 = c1 ? i1 : (c2 ? m : i2);
          i1 = c0 ? i0 : (c1 ? m : i1);
          i0 = c0 ? m : i0;
          d2 = __builtin_amdgcn_fmed3f(d, d1, d2);
          d1 = __builtin_amdgcn_fmed3f(d, d0, d1);
          d0 = fminf(d, d0);
        }
      }
    }
    i0 += sub * 128; i1 += sub * 128; i2 += sub * 128;
  }

  // ---- stable butterfly merge across 8 subs ----
#pragma unroll
  for (int mk = 1; mk <= 4; mk <<= 1) {
    const float pd0 = __shfl_xor(d0, mk), pd1 = __shfl_xor(d1, mk), pd2 = __shfl_xor(d2, mk);
    const int   pi0 = __shfl_xor(i0, mk), pi1 = __shfl_xor(i1, mk), pi2 = __shfl_xor(i2, mk);
    const bool lo = (sub & mk) == 0;
    const float a0 = lo ? d0 : pd0, a1 = lo ? d1 : pd1, a2 = lo ? d2 : pd2;
    const float b0 = lo ? pd0 : d0, b1v = lo ? pd1 : d1, b2v = lo ? pd2 : d2;
    const int   A0 = lo ? i0 : pi0, A1 = lo ? i1 : pi1, A2 = lo ? i2 : pi2;
    const int   B0 = lo ? pi0 : i0, B1 = lo ? pi1 : i1, B2 = lo ? pi2 : i2;
    const bool c0 = b0 < a0;
    const bool cb1a0 = b1v < a0, cb0a1 = b0 < a1;
    const bool cb1a1 = b1v < a1, cb2a0 = b2v < a0, cb0a2 = b0 < a2;
    const float m0 = c0 ? b0 : a0;                 const int M0 = c0 ? B0 : A0;
    const float t1a = cb1a0 ? b1v : a0;            const int T1a = cb1a0 ? B1 : A0;
    const float t1b = cb0a1 ? b0 : a1;             const int T1b = cb0a1 ? B0 : A1;
    const float m1 = c0 ? t1a : t1b;               const int M1 = c0 ? T1a : T1b;
    const float sA = cb2a0 ? b2v : a0;             const int SA = cb2a0 ? B2 : A0;
    const float sB = cb1a1 ? b1v : a1;             const int SB = cb1a1 ? B1 : A1;
    const float sD = cb0a2 ? b0 : a2;              const int SD = cb0a2 ? B0 : A2;
    const float m2 = c0 ? (cb1a0 ? sA : sB) : (cb0a1 ? sB : sD);
    const int   M2 = c0 ? (cb1a0 ? SA : SB) : (cb0a1 ? SB : SD);
    d0 = m0; d1 = m1; d2 = m2; i0 = M0; i1 = M1; i2 = M2;
  }

  // ---- weights; sub0 publishes idx/w to LDS ----
  if (sub == 0) {
    const float t0 = sqrtf(fmaxf(d0, 0.f)), t1 = sqrtf(fmaxf(d1, 0.f)),
                t2 = sqrtf(fmaxf(d2, 0.f));
    const float r0 = 1.0f / (t0 + 1e-8f), r1 = 1.0f / (t1 + 1e-8f),
                r2 = 1.0f / (t2 + 1e-8f);
    const float rs = __fadd_rn(__fadd_rn(r0, r1), r2);
    idx_s[q * 3 + 0] = i0; idx_s[q * 3 + 1] = i1; idx_s[q * 3 + 2] = i2;
    w_s[q * 3 + 0] = r0 / rs; w_s[q * 3 + 1] = r1 / rs; w_s[q * 3 + 2] = r2 / rs;
  }
  __syncthreads();   // barrier 2: idx/w + pfB visible; pts dead

  const int c = l & 15, g = l >> 4;

  f32x4 acc[4][2];
#pragma unroll
  for (int i = 0; i < 4; ++i)
#pragma unroll
    for (int j = 0; j < 2; ++j) acc[i][j] = (f32x4){0.f, 0.f, 0.f, 0.f};

  // ---- up-part: gather G^T rows straight into acc (f32) ----
  {
    const float* gtb = Gt + (size_t)b * M_PTS * C2;
#pragma unroll
    for (int j = 0; j < 2; ++j) {
      const int nq = j * 16 + c;
      const int j0 = idx_s[nq * 3 + 0], j1 = idx_s[nq * 3 + 1], j2 = idx_s[nq * 3 + 2];
      const float w0 = w_s[nq * 3 + 0], w1 = w_s[nq * 3 + 1], w2 = w_s[nq * 3 + 2];
      const float* g0p = gtb + (size_t)j0 * C2 + wv * 64 + g * 4;
      const float* g1p = gtb + (size_t)j1 * C2 + wv * 64 + g * 4;
      const float* g2p = gtb + (size_t)j2 * C2 + wv * 64 + g * 4;
#pragma unroll
      for (int i = 0; i < 4; ++i) {
        const float4 f0 = *(const float4*)(g0p + i * 16);
        const float4 f1 = *(const float4*)(g1p + i * 16);
        const float4 f2 = *(const float4*)(g2p + i * 16);
        acc[i][j].x += w0 * f0.x + w1 * f1.x + w2 * f2.x;
        acc[i][j].y += w0 * f0.y + w1 * f1.y + w2 * f2.y;
        acc[i][j].z += w0 * f0.z + w1 * f1.z + w2 * f2.z;
        acc[i][j].w += w0 * f0.w + w1 * f1.w + w2 * f2.w;
      }
    }
  }

  // ---------------- GEMM1 (skip only): K = 128, W1f kb 8..11 ----------------
  for (int kb = 0; kb < 4; ++kb) {
    const int kqg = kb * 4 + g;
    bf16x8 bfr[2], afr[4];
#pragma unroll
    for (int j = 0; j < 2; ++j)
      bfr[j] = *reinterpret_cast<const bf16x8*>(&pfB[(kqg * 32 + ((j * 16 + c) ^ (kqg & 7))) * 8]);
#pragma unroll
    for (int i = 0; i < 4; ++i)
      afr[i] = *reinterpret_cast<const bf16x8*>(&W1f[(((wv * 4 + i) * 12 + kb + 8) * 4 + g) * 128 + c * 8]);
    __builtin_amdgcn_s_setprio(1);
#pragma unroll
    for (int i = 0; i < 4; ++i)
#pragma unroll
      for (int j = 0; j < 2; ++j)
        acc[i][j] = __builtin_amdgcn_mfma_f32_16x16x32_bf16(afr[i], bfr[j], acc[i][j], 0, 0, 0);
    __builtin_amdgcn_s_setprio(0);
  }

  // h -> hbuf (aliases pts; dead since barrier 2)
#pragma unroll
  for (int i = 0; i < 4; ++i) {
    const int mbase = wv * 64 + i * 16 + g * 4;
    const float4 bias = *(const float4*)(b1 + mbase);
#pragma unroll
    for (int j = 0; j < 2; ++j) {
      const int nn = j * 16 + c;
      const int kq = mbase >> 3;
      const int u = kq * 32 + (nn ^ (kq & 7));
      ushort4 hv;
      hv.x = bf16c(fmaxf(acc[i][j].x + bias.x, 0.f));
      hv.y = bf16c(fmaxf(acc[i][j].y + bias.y, 0.f));
      hv.z = bf16c(fmaxf(acc[i][j].z + bias.z, 0.f));
      hv.w = bf16c(fmaxf(acc[i][j].w + bias.w, 0.f));
      *reinterpret_cast<ushort4*>(&hbuf[u * 8 + (mbase & 7)]) = hv;
    }
  }
  __syncthreads();   // barrier 3: h complete

#pragma unroll
  for (int i = 0; i < 4; ++i)
#pragma unroll
    for (int j = 0; j < 2; ++j) acc[i][j] = (f32x4){0.f, 0.f, 0.f, 0.f};

  // ---------------- GEMM2: out = relu(W2 @ h + b2), K = 256 ----------------
  {
    bf16x8 afr[4], nafr[4];
#pragma unroll
    for (int i = 0; i < 4; ++i)
      afr[i] = *reinterpret_cast<const bf16x8*>(&W2f[(((wv * 4 + i) * 8 + 0) * 4 + g) * 128 + c * 8]);
    for (int kb = 0; kb < 8; ++kb) {
      const int kqg = kb * 4 + g;
      bf16x8 bfr[2];
#pragma unroll
      for (int j = 0; j < 2; ++j)
        bfr[j] = *reinterpret_cast<const bf16x8*>(&hbuf[(kqg * 32 + ((j * 16 + c) ^ (kqg & 7))) * 8]);
      if (kb < 7) {
#pragma unroll
        for (int i = 0; i < 4; ++i)
          nafr[i] = *reinterpret_cast<const bf16x8*>(&W2f[(((wv * 4 + i) * 8 + kb + 1) * 4 + g) * 128 + c * 8]);
      }
      __builtin_amdgcn_s_setprio(1);
#pragma unroll
      for (int i = 0; i < 4; ++i)
#pragma unroll
        for (int j = 0; j < 2; ++j)
          acc[i][j] = __builtin_amdgcn_mfma_f32_16x16x32_bf16(afr[i], bfr[j], acc[i][j], 0, 0, 0);
      __builtin_amdgcn_s_setprio(0);
      if (kb < 7) {
#pragma unroll
        for (int i = 0; i < 4; ++i) afr[i] = nafr[i];
      }
    }
  }

  // epilogue: relu(acc + b2) -> out
#pragma unroll
  for (int i = 0; i < 4; ++i) {
    const int mbase = wv * 64 + i * 16 + g * 4;
    const float4 bias = *(const float4*)(b2 + mbase);
#pragma unroll
    for (int j = 0; j < 2; ++j) {
      const int nn = n0 + j * 16 + c;
      out[((size_t)b * C2 + mbase + 0) * N_PTS + nn] = fmaxf(acc[i][j].x + bias.x, 0.f);
      out[((size_t)b * C2 + mbase + 1) * N_PTS + nn] = fmaxf(acc[i][j].y + bias.y, 0.f);
      out[((size_t)b * C2 + mbase + 2) * N_PTS + nn] = fmaxf(acc[i][j].z + bias.z, 0.f);
      out[((size_t)b * C2 + mbase + 3) * N_PTS + nn] = fmaxf(acc[i][j].w + bias.w, 0.f);
    }
  }
}

// ---------------------------------------------------------------------------
extern "C" void kernel_launch(void* const* d_in, const int* in_sizes, int n_in,
                              void* d_out, int out_size, void* d_ws, size_t ws_size,
                              hipStream_t stream) {
  const float* xyz   = (const float*)d_in[0];
  const float* pxyz  = (const float*)d_in[1];
  const float* feats = (const float*)d_in[2];
  const float* skip  = (const float*)d_in[3];
  const float* W1    = (const float*)d_in[4];
  const float* b1    = (const float*)d_in[5];
  const float* W2    = (const float*)d_in[6];
  const float* b2    = (const float*)d_in[7];
  float* out = (float*)d_out;

  ushort* W1f = (ushort*)d_ws;                                   // 98304 ushort
  ushort* W2f = W1f + (size_t)C2 * K1DIM;                        // 65536 ushort
  float*  Gt  = (float*)(W2f + (size_t)C2 * C2);                 // 8*1024*256 f32

  prep_k<<<512, 256, 0, stream>>>(feats, W1, W2, W1f, W2f, Gt);
  fp_fused_k<<<BS * (N_PTS / 32), 256, 0, stream>>>(xyz, pxyz, Gt, skip,
                                                    W1f, b1, W2f, b2, out);
}